// Round 2
// baseline (662.202 us; speedup 1.0000x reference)
//
#include <hip/hip_runtime.h>
#include <math.h>

#define IMG_W 384
#define IMG_H 384
#define IMG_HW (IMG_W * IMG_H)
#define N_IMG 512   /* B*C */
#define N_CH 64
#define N_B 8
#define POOL_PARTS 4
#define POOL_BLOCKS (N_IMG * POOL_PARTS)

typedef float f4v __attribute__((ext_vector_type(4)));

// ------- Kernel 1: partial pool (reverse sweep) + last-block MLP params -------
// 4 blocks per (b,c); bc swept 511 -> 0 so the LLC ends holding the FIRST
// ~256 MiB of x, which the conv kernel (forward sweep) then re-reads as hits.
// Last block (device-scope atomic counter) reduces partials and runs the MLP.
__global__ __launch_bounds__(256) void pool_params_kernel(
        const float* __restrict__ x,
        const float* __restrict__ w1, const float* __restrict__ b1,
        const float* __restrict__ w2, const float* __restrict__ b2,
        float* __restrict__ partial, float* __restrict__ guv,
        unsigned int* __restrict__ counter) {
    const int blk = blockIdx.x;           // 0..2047
    const int bc = (N_IMG - 1) - (blk >> 2);   // reverse sweep over images
    const int part = blk & 3;
    const float4* xp = (const float4*)(x + (size_t)bc * IMG_HW + part * (IMG_HW / POOL_PARTS));
    const int t = threadIdx.x;
    float s0 = 0.f, s1 = 0.f;
    #pragma unroll
    for (int k = 0; k < 36; k += 2) {
        float4 a = xp[t + k * 256];
        float4 b = xp[t + (k + 1) * 256];
        s0 += (a.x + a.y) + (a.z + a.w);
        s1 += (b.x + b.y) + (b.z + b.w);
    }
    float s = s0 + s1;
    #pragma unroll
    for (int off = 32; off > 0; off >>= 1) s += __shfl_down(s, off, 64);
    __shared__ float red[4];
    __shared__ unsigned int lastflag;
    if ((t & 63) == 0) red[t >> 6] = s;
    __syncthreads();
    if (t == 0) {
        partial[bc * 4 + part] = (red[0] + red[1]) + (red[2] + red[3]);
        __threadfence();                          // release partial write
        unsigned int old = atomicAdd(counter, 1u);
        lastflag = (old == POOL_BLOCKS - 1) ? 1u : 0u;
    }
    __syncthreads();
    if (!lastflag) return;

    // ---- last block: reduce partials, run MLP, emit separable taps ----
    __threadfence();                              // acquire all partials
    __shared__ float pooled[N_IMG];
    #pragma unroll
    for (int i = 0; i < 2; ++i) {
        int img = t + i * 256;
        float4 pp = *(const float4*)(partial + img * 4);
        pooled[img] = (pp.x + pp.y + pp.z + pp.w) * (1.0f / (float)IMG_HW);
    }
    __syncthreads();
    const int b = t;
    if (b >= N_B) return;
    const float* P = &pooled[b * N_CH];
    float h[16];
    #pragma unroll
    for (int j = 0; j < 16; ++j) {
        float acc = b1[j];
        for (int c = 0; c < N_CH; ++c) acc += P[c] * w1[j * N_CH + c];
        h[j] = acc / (1.f + expf(-acc));          // SiLU
    }
    float p[3];
    #pragma unroll
    for (int k = 0; k < 3; ++k) {
        float acc = b2[k];
        #pragma unroll
        for (int j = 0; j < 16; ++j) acc += h[j] * w2[k * 16 + j];
        p[k] = acc;
    }
    float sigma = (p[0] > 20.f) ? p[0] : log1pf(expf(p[0]));  // softplus
    float dx = tanhf(p[1]) * 2.f;
    float dy = tanhf(p[2]) * 2.f;
    float cx = 3.f + dx, cy = 3.f + dy;
    float inv2s2 = 1.f / (2.f * sigma * sigma);
    float u[7], v[7], su = 0.f, sv = 0.f;
    #pragma unroll
    for (int i = 0; i < 7; ++i) { float d = (float)i - cx; u[i] = expf(-d * d * inv2s2); su += u[i]; }
    #pragma unroll
    for (int j = 0; j < 7; ++j) { float d = (float)j - cy; v[j] = expf(-d * d * inv2s2); sv += v[j]; }
    float rsu = 1.f / su, rsv = 1.f / sv;
    #pragma unroll
    for (int i = 0; i < 7; ++i) guv[b * 14 + i] = u[i] * rsu;
    #pragma unroll
    for (int j = 0; j < 7; ++j) guv[b * 14 + 7 + j] = v[j] * rsv;
}

// ---------------- Kernel 2: separable 7x7 conv, float4 per thread ------
// Forward sweep (LLC hits from pool's reverse sweep). Non-temporal output
// stores so the 302 MB of write-once output doesn't evict x from the LLC.
#define BANDS 2
#define BAND_ROWS 192
#define GROUP_ROWS 48
#define NITER 27            /* 3 prime + 24 compute iterations, 2 rows each */
#define LROW 392

__global__ __launch_bounds__(384) void conv_kernel(const float* __restrict__ x,
                                                   const float* __restrict__ guv,
                                                   float* __restrict__ out) {
    __shared__ float buf[2][8][LROW];
    const int tid = threadIdx.x;
    const int tx = tid % 96;
    const int ty = tid / 96;
    const int blk = blockIdx.x;
    const int bc = blk >> 1;
    const int band = blk & 1;
    const int b = bc >> 6;
    const float* img = x + (size_t)bc * IMG_HW;
    float* oimg = out + (size_t)bc * IMG_HW;
    const int base4 = 4 * tx;            // first float of this thread's quad
    const int gbase = band * BAND_ROWS + ty * GROUP_ROWS;

    float u[7], v[7];
    #pragma unroll
    for (int i = 0; i < 7; ++i) { u[i] = guv[b * 14 + i]; v[i] = guv[b * 14 + 7 + i]; }

    // zero the pad columns of all 16 buffer rows (once)
    if (tid < 128) {
        int r = tid >> 3;                  // 0..15
        int p = tid & 7;                   // 0..7
        int col = (p < 4) ? p : (384 + p); // 0..3 or 388..391
        buf[r >> 3][r & 7][col] = 0.f;
    }

    // Prologue staging into buf[0]
    #pragma unroll
    for (int k = 0; k < 2; ++k) {
        int s = ty + 4 * k;
        int g = s >> 1, sub = s & 1;
        int row = band * BAND_ROWS + g * GROUP_ROWS - 3 + sub;
        float4 val = make_float4(0.f, 0.f, 0.f, 0.f);
        if (row >= 0 && row < IMG_H) val = *(const float4*)(img + row * IMG_W + base4);
        *(float4*)&buf[0][s][4 + base4] = val;
    }
    __syncthreads();

    float4 h[6];
    #pragma unroll
    for (int k = 0; k < 6; ++k) h[k] = make_float4(0.f, 0.f, 0.f, 0.f);

    #pragma unroll 3
    for (int it = 0; it < NITER; ++it) {
        // issue next iteration's staging loads into registers
        float4 nv[2];
        const bool have_next = (it + 1 < NITER);
        if (have_next) {
            #pragma unroll
            for (int k = 0; k < 2; ++k) {
                int s = ty + 4 * k;
                int g = s >> 1, sub = s & 1;
                int row = band * BAND_ROWS + g * GROUP_ROWS + 2 * (it + 1) - 3 + sub;
                nv[k] = make_float4(0.f, 0.f, 0.f, 0.f);
                if (row >= 0 && row < IMG_H) nv[k] = *(const float4*)(img + row * IMG_W + base4);
            }
        }
        // compute 2 rows for this group from buf[it&1] slots ty*2, ty*2+1
        const float (*cb)[LROW] = buf[it & 1];
        #pragma unroll
        for (int r = 0; r < 2; ++r) {
            const float* rp = &cb[ty * 2 + r][base4];
            float4 a  = *(const float4*)(rp);
            float4 bq = *(const float4*)(rp + 4);
            float4 cq = *(const float4*)(rp + 8);
            float wv[12] = {a.x, a.y, a.z, a.w, bq.x, bq.y, bq.z, bq.w,
                            cq.x, cq.y, cq.z, cq.w};
            float4 hn;
            hn.x = u[0]*wv[1] + u[1]*wv[2] + u[2]*wv[3] + u[3]*wv[4] + u[4]*wv[5] + u[5]*wv[6] + u[6]*wv[7];
            hn.y = u[0]*wv[2] + u[1]*wv[3] + u[2]*wv[4] + u[3]*wv[5] + u[4]*wv[6] + u[5]*wv[7] + u[6]*wv[8];
            hn.z = u[0]*wv[3] + u[1]*wv[4] + u[2]*wv[5] + u[3]*wv[6] + u[4]*wv[7] + u[5]*wv[8] + u[6]*wv[9];
            hn.w = u[0]*wv[4] + u[1]*wv[5] + u[2]*wv[6] + u[3]*wv[7] + u[4]*wv[8] + u[5]*wv[9] + u[6]*wv[10];
            if (it >= 3) {
                const int y = gbase + 2 * (it - 3) + r;
                f4v o;
                o.x = v[0]*h[0].x + v[1]*h[1].x + v[2]*h[2].x + v[3]*h[3].x + v[4]*h[4].x + v[5]*h[5].x + v[6]*hn.x;
                o.y = v[0]*h[0].y + v[1]*h[1].y + v[2]*h[2].y + v[3]*h[3].y + v[4]*h[4].y + v[5]*h[5].y + v[6]*hn.y;
                o.z = v[0]*h[0].z + v[1]*h[1].z + v[2]*h[2].z + v[3]*h[3].z + v[4]*h[4].z + v[5]*h[5].z + v[6]*hn.z;
                o.w = v[0]*h[0].w + v[1]*h[1].w + v[2]*h[2].w + v[3]*h[3].w + v[4]*h[4].w + v[5]*h[5].w + v[6]*hn.w;
                __builtin_nontemporal_store(o, (f4v*)(oimg + y * IMG_W + base4));
            }
            #pragma unroll
            for (int k2 = 0; k2 < 5; ++k2) h[k2] = h[k2 + 1];
            h[5] = hn;
        }
        // write staged registers into the alternate buffer (after compute)
        if (have_next) {
            float (*bn)[LROW] = buf[(it + 1) & 1];
            #pragma unroll
            for (int k = 0; k < 2; ++k) {
                int s = ty + 4 * k;
                *(float4*)&bn[s][4 + base4] = nv[k];
            }
        }
        __syncthreads();
    }
}

extern "C" void kernel_launch(void* const* d_in, const int* in_sizes, int n_in,
                              void* d_out, int out_size, void* d_ws, size_t ws_size,
                              hipStream_t stream) {
    const float* x  = (const float*)d_in[0];
    const float* w1 = (const float*)d_in[1];
    const float* b1 = (const float*)d_in[2];
    const float* w2 = (const float*)d_in[3];
    const float* b2 = (const float*)d_in[4];
    float* outp = (float*)d_out;

    float* partial = (float*)d_ws;                 // 2048 floats
    float* guv     = partial + 2048;               // 112 floats
    unsigned int* counter = (unsigned int*)(guv + 112);

    hipMemsetAsync(counter, 0, sizeof(unsigned int), stream);
    pool_params_kernel<<<POOL_BLOCKS, 256, 0, stream>>>(x, w1, b1, w2, b2,
                                                        partial, guv, counter);
    conv_kernel<<<N_IMG * BANDS, 384, 0, stream>>>(x, guv, outp);
}

// Round 3
// 576.808 us; speedup vs baseline: 1.1480x; 1.1480x over previous
//
#include <hip/hip_runtime.h>
#include <math.h>

#define IMG_W 384
#define IMG_H 384
#define IMG_HW (IMG_W * IMG_H)
#define N_IMG 512   /* B*C */
#define N_CH 64
#define N_B 8
#define POOL_PARTS 4

typedef float f4v __attribute__((ext_vector_type(4)));

// ---------------- Kernel 1: partial global average pool (reverse sweep) -----
// 4 blocks per (b,c) image. bc swept 511 -> 0 so the LLC ends holding the
// FIRST ~256 MiB of x, which the conv kernel (forward sweep) re-reads as hits.
// No atomics / no fences: one-block atomic chains cost ~200 us (measured R2).
__global__ __launch_bounds__(256) void pool_kernel(const float* __restrict__ x,
                                                   float* __restrict__ partial) {
    const int blk = blockIdx.x;                  // 0..2047
    const int bc = (N_IMG - 1) - (blk >> 2);     // reverse sweep over images
    const int part = blk & 3;
    const float4* xp = (const float4*)(x + (size_t)bc * IMG_HW + part * (IMG_HW / POOL_PARTS));
    const int t = threadIdx.x;
    float s0 = 0.f, s1 = 0.f;
    // 36864 floats = 9216 float4 / 256 threads = 36 per thread, coalesced
    #pragma unroll
    for (int k = 0; k < 36; k += 2) {
        float4 a = xp[t + k * 256];
        float4 b = xp[t + (k + 1) * 256];
        s0 += (a.x + a.y) + (a.z + a.w);
        s1 += (b.x + b.y) + (b.z + b.w);
    }
    float s = s0 + s1;
    #pragma unroll
    for (int off = 32; off > 0; off >>= 1) s += __shfl_down(s, off, 64);
    __shared__ float red[4];
    if ((t & 63) == 0) red[t >> 6] = s;
    __syncthreads();
    if (t == 0) partial[bc * 4 + part] = (red[0] + red[1]) + (red[2] + red[3]);
}

// ---------------- Kernel 2: reduce partials + MLP -> separable taps ----
// guv layout per sample b: [u0..u6, v0..v6]
__global__ __launch_bounds__(512) void params_kernel(const float* __restrict__ partial,
                              const float* __restrict__ w1, const float* __restrict__ b1,
                              const float* __restrict__ w2, const float* __restrict__ b2,
                              float* __restrict__ guv) {
    __shared__ float pooled[N_IMG];
    const int t = threadIdx.x;
    {
        float4 pp = *(const float4*)(partial + t * 4);
        pooled[t] = (pp.x + pp.y + pp.z + pp.w) * (1.0f / (float)IMG_HW);
    }
    __syncthreads();
    const int b = t;
    if (b >= N_B) return;
    const float* P = &pooled[b * N_CH];
    float h[16];
    #pragma unroll
    for (int j = 0; j < 16; ++j) {
        float acc = b1[j];
        for (int c = 0; c < N_CH; ++c) acc += P[c] * w1[j * N_CH + c];
        h[j] = acc / (1.f + expf(-acc));       // SiLU
    }
    float p[3];
    #pragma unroll
    for (int k = 0; k < 3; ++k) {
        float acc = b2[k];
        #pragma unroll
        for (int j = 0; j < 16; ++j) acc += h[j] * w2[k * 16 + j];
        p[k] = acc;
    }
    float sigma = (p[0] > 20.f) ? p[0] : log1pf(expf(p[0]));  // softplus
    float dx = tanhf(p[1]) * 2.f;
    float dy = tanhf(p[2]) * 2.f;
    float cx = 3.f + dx, cy = 3.f + dy;
    float inv2s2 = 1.f / (2.f * sigma * sigma);
    float u[7], v[7], su = 0.f, sv = 0.f;
    #pragma unroll
    for (int i = 0; i < 7; ++i) { float d = (float)i - cx; u[i] = expf(-d * d * inv2s2); su += u[i]; }
    #pragma unroll
    for (int j = 0; j < 7; ++j) { float d = (float)j - cy; v[j] = expf(-d * d * inv2s2); sv += v[j]; }
    float rsu = 1.f / su, rsv = 1.f / sv;
    #pragma unroll
    for (int i = 0; i < 7; ++i) guv[b * 14 + i] = u[i] * rsu;
    #pragma unroll
    for (int j = 0; j < 7; ++j) guv[b * 14 + 7 + j] = v[j] * rsv;
}

// ---------------- Kernel 3: separable 7x7 conv, float4 per thread ------
// Forward sweep (LLC hits from pool's reverse sweep). Non-temporal output
// stores so the 302 MB of write-once output doesn't evict x from the LLC.
#define BANDS 2
#define BAND_ROWS 192
#define GROUP_ROWS 48
#define NITER 27            /* 3 prime + 24 compute iterations, 2 rows each */
#define LROW 392

__global__ __launch_bounds__(384) void conv_kernel(const float* __restrict__ x,
                                                   const float* __restrict__ guv,
                                                   float* __restrict__ out) {
    __shared__ float buf[2][8][LROW];
    const int tid = threadIdx.x;
    const int tx = tid % 96;
    const int ty = tid / 96;
    const int blk = blockIdx.x;
    const int bc = blk >> 1;
    const int band = blk & 1;
    const int b = bc >> 6;
    const float* img = x + (size_t)bc * IMG_HW;
    float* oimg = out + (size_t)bc * IMG_HW;
    const int base4 = 4 * tx;            // first float of this thread's quad
    const int gbase = band * BAND_ROWS + ty * GROUP_ROWS;

    float u[7], v[7];
    #pragma unroll
    for (int i = 0; i < 7; ++i) { u[i] = guv[b * 14 + i]; v[i] = guv[b * 14 + 7 + i]; }

    // zero the pad columns of all 16 buffer rows (once)
    if (tid < 128) {
        int r = tid >> 3;                  // 0..15
        int p = tid & 7;                   // 0..7
        int col = (p < 4) ? p : (384 + p); // 0..3 or 388..391
        buf[r >> 3][r & 7][col] = 0.f;
    }

    // Prologue staging into buf[0]
    #pragma unroll
    for (int k = 0; k < 2; ++k) {
        int s = ty + 4 * k;
        int g = s >> 1, sub = s & 1;
        int row = band * BAND_ROWS + g * GROUP_ROWS - 3 + sub;
        float4 val = make_float4(0.f, 0.f, 0.f, 0.f);
        if (row >= 0 && row < IMG_H) val = *(const float4*)(img + row * IMG_W + base4);
        *(float4*)&buf[0][s][4 + base4] = val;
    }
    __syncthreads();

    float4 h[6];
    #pragma unroll
    for (int k = 0; k < 6; ++k) h[k] = make_float4(0.f, 0.f, 0.f, 0.f);

    #pragma unroll 3
    for (int it = 0; it < NITER; ++it) {
        // issue next iteration's staging loads into registers
        float4 nv[2];
        const bool have_next = (it + 1 < NITER);
        if (have_next) {
            #pragma unroll
            for (int k = 0; k < 2; ++k) {
                int s = ty + 4 * k;
                int g = s >> 1, sub = s & 1;
                int row = band * BAND_ROWS + g * GROUP_ROWS + 2 * (it + 1) - 3 + sub;
                nv[k] = make_float4(0.f, 0.f, 0.f, 0.f);
                if (row >= 0 && row < IMG_H) nv[k] = *(const float4*)(img + row * IMG_W + base4);
            }
        }
        // compute 2 rows for this group from buf[it&1] slots ty*2, ty*2+1
        const float (*cb)[LROW] = buf[it & 1];
        #pragma unroll
        for (int r = 0; r < 2; ++r) {
            const float* rp = &cb[ty * 2 + r][base4];
            float4 a  = *(const float4*)(rp);
            float4 bq = *(const float4*)(rp + 4);
            float4 cq = *(const float4*)(rp + 8);
            float wv[12] = {a.x, a.y, a.z, a.w, bq.x, bq.y, bq.z, bq.w,
                            cq.x, cq.y, cq.z, cq.w};
            float4 hn;
            hn.x = u[0]*wv[1] + u[1]*wv[2] + u[2]*wv[3] + u[3]*wv[4] + u[4]*wv[5] + u[5]*wv[6] + u[6]*wv[7];
            hn.y = u[0]*wv[2] + u[1]*wv[3] + u[2]*wv[4] + u[3]*wv[5] + u[4]*wv[6] + u[5]*wv[7] + u[6]*wv[8];
            hn.z = u[0]*wv[3] + u[1]*wv[4] + u[2]*wv[5] + u[3]*wv[6] + u[4]*wv[7] + u[5]*wv[8] + u[6]*wv[9];
            hn.w = u[0]*wv[4] + u[1]*wv[5] + u[2]*wv[6] + u[3]*wv[7] + u[4]*wv[8] + u[5]*wv[9] + u[6]*wv[10];
            if (it >= 3) {
                const int y = gbase + 2 * (it - 3) + r;
                f4v o;
                o.x = v[0]*h[0].x + v[1]*h[1].x + v[2]*h[2].x + v[3]*h[3].x + v[4]*h[4].x + v[5]*h[5].x + v[6]*hn.x;
                o.y = v[0]*h[0].y + v[1]*h[1].y + v[2]*h[2].y + v[3]*h[3].y + v[4]*h[4].y + v[5]*h[5].y + v[6]*hn.y;
                o.z = v[0]*h[0].z + v[1]*h[1].z + v[2]*h[2].z + v[3]*h[3].z + v[4]*h[4].z + v[5]*h[5].z + v[6]*hn.z;
                o.w = v[0]*h[0].w + v[1]*h[1].w + v[2]*h[2].w + v[3]*h[3].w + v[4]*h[4].w + v[5]*h[5].w + v[6]*hn.w;
                __builtin_nontemporal_store(o, (f4v*)(oimg + y * IMG_W + base4));
            }
            #pragma unroll
            for (int k2 = 0; k2 < 5; ++k2) h[k2] = h[k2 + 1];
            h[5] = hn;
        }
        // write staged registers into the alternate buffer (after compute)
        if (have_next) {
            float (*bn)[LROW] = buf[(it + 1) & 1];
            #pragma unroll
            for (int k = 0; k < 2; ++k) {
                int s = ty + 4 * k;
                *(float4*)&bn[s][4 + base4] = nv[k];
            }
        }
        __syncthreads();
    }
}

extern "C" void kernel_launch(void* const* d_in, const int* in_sizes, int n_in,
                              void* d_out, int out_size, void* d_ws, size_t ws_size,
                              hipStream_t stream) {
    const float* x  = (const float*)d_in[0];
    const float* w1 = (const float*)d_in[1];
    const float* b1 = (const float*)d_in[2];
    const float* w2 = (const float*)d_in[3];
    const float* b2 = (const float*)d_in[4];
    float* outp = (float*)d_out;

    float* partial = (float*)d_ws;                 // 2048 floats
    float* guv     = partial + 2048;               // 112 floats

    pool_kernel<<<N_IMG * POOL_PARTS, 256, 0, stream>>>(x, partial);
    params_kernel<<<1, 512, 0, stream>>>(partial, w1, b1, w2, b2, guv);
    conv_kernel<<<N_IMG * BANDS, 384, 0, stream>>>(x, guv, outp);
}